// Round 5
// baseline (117.122 us; speedup 1.0000x reference)
//
#include <hip/hip_runtime.h>

#define BATCH 8
#define NPTS 4096
#define TOTQ (BATCH * NPTS)
#define TPB 256
#define BIGD 1e30f

// ---- shared arithmetic: MUST be bitwise identical between scan and rescan ----
// candidate m staged/recomputed as (cx,cy,cz,w) = (-2x, -2y, -2z, x^2+y^2+z^2)
// key(n,m) = w_m - 2*dot(p_n,p_m) = d^2 - |p_n|^2  (monotone in d, 3 FMAs)
__device__ __forceinline__ float cand_w(float x, float y, float z) {
    return fmaf(x, x, fmaf(y, y, z * z));
}
__device__ __forceinline__ float cand_key(float cx, float cy, float cz, float w,
                                          float xn, float yn, float zn) {
    return fmaf(cx, xn, fmaf(cy, yn, fmaf(cz, zn, w)));
}

// Branchless stable top-2 (min) with payload. Invariant b1 <= b2. Strict <
// keeps the earlier-fed candidate on exact ties (== jax.lax.top_k
// lowest-index rule when fed in ascending index order).
__device__ __forceinline__ void top2min(float k, int m,
                                        float& b1, int& i1,
                                        float& b2, int& i2) {
    bool c1 = k < b1;
    bool c2 = k < b2;
    int ni2 = c2 ? m : i2;
    i2 = c1 ? i1 : ni2;
    i1 = c1 ? m : i1;
    b2 = fminf(fmaxf(k, b1), b2);   // med3(b1,b2,k) given b1<=b2
    b1 = fminf(k, b1);
}

// Pass 1: VALUES ONLY (no index tracking, no self exclusion — self key is the
// strict global min and is handled in the merge). 5 VALU/pair core.
// block = (query tile of TPB*Q, candidate chunk of NPTS/NCHUNKS, batch).
template <int NCHUNKS, int Q>
__global__ __launch_bounds__(TPB, 4) void knn_scan(const float* __restrict__ coords,
                                                   float2* __restrict__ partial) {
    constexpr int CHUNKSZ = NPTS / NCHUNKS;
    __shared__ float4 pts[CHUNKSZ];
    const int tid   = (int)threadIdx.x;
    const int tile  = blockIdx.x;
    const int chunk = blockIdx.y;
    const int b     = blockIdx.z;
    const float* basep = coords + (size_t)b * NPTS * 3;
    const int mbase = chunk * CHUNKSZ;

    for (int p = tid; p < CHUNKSZ; p += TPB) {
        float x = basep[(mbase + p) * 3 + 0];
        float y = basep[(mbase + p) * 3 + 1];
        float z = basep[(mbase + p) * 3 + 2];
        pts[p] = make_float4(-2.0f * x, -2.0f * y, -2.0f * z, cand_w(x, y, z));
    }

    const int qbase = tile * (TPB * Q);
    float xn[Q], yn[Q], zn[Q], b1[Q], b2[Q];
#pragma unroll
    for (int q = 0; q < Q; ++q) {
        int n = qbase + q * TPB + tid;
        xn[q] = basep[n * 3 + 0];
        yn[q] = basep[n * 3 + 1];
        zn[q] = basep[n * 3 + 2];
        b1[q] = BIGD; b2[q] = BIGD;
    }
    __syncthreads();

    for (int p = 0; p < CHUNKSZ; p += 8) {
        float4 c[8];
#pragma unroll
        for (int j = 0; j < 8; ++j) c[j] = pts[p + j];
#pragma unroll
        for (int j = 0; j < 8; ++j) {
#pragma unroll
            for (int q = 0; q < Q; ++q) {
                float k = cand_key(c[j].x, c[j].y, c[j].z, c[j].w, xn[q], yn[q], zn[q]);
                b2[q] = fminf(fmaxf(k, b1[q]), b2[q]);
                b1[q] = fminf(k, b1[q]);
            }
        }
    }

#pragma unroll
    for (int q = 0; q < Q; ++q) {
        int n = qbase + q * TPB + tid;
        partial[(size_t)chunk * TOTQ + (size_t)b * NPTS + n] = make_float2(b1[q], b2[q]);
    }
}

// Rescan one chunk from global coords with full index tracking, bitwise
// identical key arithmetic, excluding self. Feeds ascending m (stable).
template <int CHUNKSZ>
__device__ __forceinline__ void rescan_chunk(const float* __restrict__ basep, int c, int n,
                                             float xn, float yn, float zn,
                                             float& r1, int& j1, float& r2, int& j2) {
    r1 = BIGD; r2 = BIGD; j1 = 0; j2 = 0;
    const int m0 = c * CHUNKSZ;
    for (int m = m0; m < m0 + CHUNKSZ; ++m) {
        float x = basep[m * 3 + 0];
        float y = basep[m * 3 + 1];
        float z = basep[m * 3 + 2];
        float w = cand_w(x, y, z);
        float k = cand_key(-2.0f * x, -2.0f * y, -2.0f * z, w, xn, yn, zn);
        k = (m == n) ? BIGD : k;
        top2min(k, m, r1, j1, r2, j2);
    }
}

// Pass 2: per query, merge chunk VALUE pairs (skipping the self chunk),
// identify the <=2 winning chunks, rescan them + the self chunk with index
// tracking, combine in ascending-chunk order, gather coords, write outputs.
template <int NCHUNKS>
__global__ __launch_bounds__(TPB) void knn_merge(const float* __restrict__ coords,
                                                 const float2* __restrict__ partial,
                                                 float* __restrict__ out) {
    constexpr int CHUNKSZ = NPTS / NCHUNKS;
    const int q = blockIdx.x * TPB + (int)threadIdx.x;  // 0..TOTQ-1
    const int b = q >> 12;
    const int n = q & (NPTS - 1);
    const float* basep = coords + (size_t)b * NPTS * 3;
    const int c_self = n / CHUNKSZ;   // wave-uniform (CHUNKSZ is a multiple of 64)

    const float xn = basep[n * 3 + 0];
    const float yn = basep[n * 3 + 1];
    const float zn = basep[n * 3 + 2];

    // Value merge with chunk attribution, self chunk skipped.
    float v1 = BIGD, v2 = BIGD;
    int ca = (c_self == 0) ? 1 : 0, cbk = ca;
    for (int c = 0; c < NCHUNKS; ++c) {
        if (c == c_self) continue;   // wave-uniform branch
        float2 v = partial[(size_t)c * TOTQ + q];
        top2min(v.x, c, v1, ca, v2, cbk);
        top2min(v.y, c, v1, ca, v2, cbk);
    }

    // Rescan set = {c_self, ca, cbk}, ascending with dedup (ca,cbk != c_self).
    int lo3 = min(min(c_self, ca), cbk);
    int hi3 = max(max(c_self, ca), cbk);
    int md3 = c_self + ca + cbk - lo3 - hi3;

    float f1 = BIGD, f2 = BIGD;
    int g1 = 0, g2 = 0;
    float r1, r2; int j1, j2;

    rescan_chunk<CHUNKSZ>(basep, lo3, n, xn, yn, zn, r1, j1, r2, j2);
    top2min(r1, j1, f1, g1, f2, g2);
    top2min(r2, j2, f1, g1, f2, g2);
    if (md3 > lo3) {
        rescan_chunk<CHUNKSZ>(basep, md3, n, xn, yn, zn, r1, j1, r2, j2);
        top2min(r1, j1, f1, g1, f2, g2);
        top2min(r2, j2, f1, g1, f2, g2);
    }
    if (hi3 > md3) {
        rescan_chunk<CHUNKSZ>(basep, hi3, n, xn, yn, zn, r1, j1, r2, j2);
        top2min(r1, j1, f1, g1, f2, g2);
        top2min(r2, j2, f1, g1, f2, g2);
    }

    float* A  = out;
    float* C  = out + (size_t)TOTQ * 3;
    float* I1 = out + (size_t)2 * TOTQ * 3;
    float* I2 = I1 + (size_t)TOTQ;

    A[(size_t)q * 3 + 0] = basep[g1 * 3 + 0];
    A[(size_t)q * 3 + 1] = basep[g1 * 3 + 1];
    A[(size_t)q * 3 + 2] = basep[g1 * 3 + 2];
    C[(size_t)q * 3 + 0] = basep[g2 * 3 + 0];
    C[(size_t)q * 3 + 1] = basep[g2 * 3 + 1];
    C[(size_t)q * 3 + 2] = basep[g2 * 3 + 2];
    I1[q] = (float)g1;
    I2[q] = (float)g2;
}

// Ultimate fallback (tiny ws): monolithic kernel, all candidates in LDS.
__global__ __launch_bounds__(TPB) void knn_full(const float* __restrict__ coords,
                                                float* __restrict__ out) {
    __shared__ float4 pts[NPTS];  // 64 KB
    const int tid  = (int)threadIdx.x;
    const int tile = blockIdx.x;
    const int b    = blockIdx.y;
    const float* basep = coords + (size_t)b * NPTS * 3;

    for (int p = tid; p < NPTS; p += TPB) {
        float x = basep[p * 3 + 0];
        float y = basep[p * 3 + 1];
        float z = basep[p * 3 + 2];
        pts[p] = make_float4(-2.0f * x, -2.0f * y, -2.0f * z, cand_w(x, y, z));
    }
    const int n = tile * TPB + tid;
    const float xn = basep[n * 3 + 0];
    const float yn = basep[n * 3 + 1];
    const float zn = basep[n * 3 + 2];
    __syncthreads();

    float b1 = BIGD, b2 = BIGD;
    int i1 = 0, i2 = 0;
    for (int p = 0; p < NPTS; p += 4) {
#pragma unroll
        for (int j = 0; j < 4; ++j) {
            float4 c = pts[p + j];
            float k = cand_key(c.x, c.y, c.z, c.w, xn, yn, zn);
            k = (p + j == n) ? BIGD : k;
            top2min(k, p + j, b1, i1, b2, i2);
        }
    }

    const int q = b * NPTS + n;
    float* A  = out;
    float* C  = out + (size_t)TOTQ * 3;
    float* I1 = out + (size_t)2 * TOTQ * 3;
    float* I2 = I1 + (size_t)TOTQ;
    float4 p1 = pts[i1];
    float4 p2 = pts[i2];
    A[(size_t)q * 3 + 0] = -0.5f * p1.x;
    A[(size_t)q * 3 + 1] = -0.5f * p1.y;
    A[(size_t)q * 3 + 2] = -0.5f * p1.z;
    C[(size_t)q * 3 + 0] = -0.5f * p2.x;
    C[(size_t)q * 3 + 1] = -0.5f * p2.y;
    C[(size_t)q * 3 + 2] = -0.5f * p2.z;
    I1[q] = (float)i1;
    I2[q] = (float)i2;
}

extern "C" void kernel_launch(void* const* d_in, const int* in_sizes, int n_in,
                              void* d_out, int out_size, void* d_ws, size_t ws_size,
                              hipStream_t stream) {
    const float* coords = (const float*)d_in[0];
    float* out = (float*)d_out;
    float2* partial = (float2*)d_ws;
    const size_t chunk_bytes = (size_t)TOTQ * sizeof(float2);  // 256 KB per chunk

    if (ws_size >= 64 * chunk_bytes) {
        // 16 MB: NCHUNKS=64, Q=8 -> grid 2*64*8 = 1024 blocks (4/CU)
        hipLaunchKernelGGL((knn_scan<64, 8>), dim3(2, 64, BATCH), dim3(TPB), 0, stream,
                           coords, partial);
        hipLaunchKernelGGL((knn_merge<64>), dim3(TOTQ / TPB), dim3(TPB), 0, stream,
                           coords, partial, out);
    } else if (ws_size >= 32 * chunk_bytes) {
        // 8 MB: NCHUNKS=32, Q=8 -> 512 blocks
        hipLaunchKernelGGL((knn_scan<32, 8>), dim3(2, 32, BATCH), dim3(TPB), 0, stream,
                           coords, partial);
        hipLaunchKernelGGL((knn_merge<32>), dim3(TOTQ / TPB), dim3(TPB), 0, stream,
                           coords, partial, out);
    } else if (ws_size >= 16 * chunk_bytes) {
        // 4 MB: NCHUNKS=16, Q=4 -> 512 blocks
        hipLaunchKernelGGL((knn_scan<16, 4>), dim3(4, 16, BATCH), dim3(TPB), 0, stream,
                           coords, partial);
        hipLaunchKernelGGL((knn_merge<16>), dim3(TOTQ / TPB), dim3(TPB), 0, stream,
                           coords, partial, out);
    } else {
        hipLaunchKernelGGL(knn_full, dim3(NPTS / TPB, BATCH), dim3(TPB), 0, stream,
                           coords, out);
    }
}

// Round 6
// 113.254 us; speedup vs baseline: 1.0342x; 1.0342x over previous
//
#include <hip/hip_runtime.h>

#define BATCH 8
#define NPTS 4096
#define TOTQ (BATCH * NPTS)
#define TPB 256
#define BIGD 1e30f

// ---- shared arithmetic: MUST be bitwise identical between scan and rescan ----
// candidate m staged as (cx,cy,cz,w) = (-2x, -2y, -2z, x^2+y^2+z^2)
// key(n,m) = w_m - 2*dot(p_n,p_m) = d^2 - |p_n|^2  (monotone in d, 3 FMAs)
__device__ __forceinline__ float cand_w(float x, float y, float z) {
    return fmaf(x, x, fmaf(y, y, z * z));
}
__device__ __forceinline__ float cand_key(float cx, float cy, float cz, float w,
                                          float xn, float yn, float zn) {
    return fmaf(cx, xn, fmaf(cy, yn, fmaf(cz, zn, w)));
}

// Branchless stable top-2 (min) with payload. Invariant b1 <= b2. Strict <
// keeps the earlier-fed candidate on exact ties (== jax.lax.top_k
// lowest-index rule when fed in ascending index order).
__device__ __forceinline__ void top2min(float k, int m,
                                        float& b1, int& i1,
                                        float& b2, int& i2) {
    bool c1 = k < b1;
    bool c2 = k < b2;
    int ni2 = c2 ? m : i2;
    i2 = c1 ? i1 : ni2;
    i1 = c1 ? m : i1;
    b2 = fminf(fmaxf(k, b1), b2);   // med3(b1,b2,k) given b1<=b2
    b1 = fminf(k, b1);
}

// Pass 1: VALUES ONLY (no index tracking, no self exclusion — self key is the
// strict global min and is handled in the merge). 5 VALU/pair core.
// block = (query tile of TPB*Q, candidate chunk of NPTS/NCHUNKS, batch).
template <int NCHUNKS, int Q>
__global__ __launch_bounds__(TPB, 4) void knn_scan(const float* __restrict__ coords,
                                                   float2* __restrict__ partial) {
    constexpr int CHUNKSZ = NPTS / NCHUNKS;
    __shared__ float4 pts[CHUNKSZ];
    const int tid   = (int)threadIdx.x;
    const int tile  = blockIdx.x;
    const int chunk = blockIdx.y;
    const int b     = blockIdx.z;
    const float* basep = coords + (size_t)b * NPTS * 3;
    const int mbase = chunk * CHUNKSZ;

    for (int p = tid; p < CHUNKSZ; p += TPB) {
        float x = basep[(mbase + p) * 3 + 0];
        float y = basep[(mbase + p) * 3 + 1];
        float z = basep[(mbase + p) * 3 + 2];
        pts[p] = make_float4(-2.0f * x, -2.0f * y, -2.0f * z, cand_w(x, y, z));
    }

    const int qbase = tile * (TPB * Q);
    float xn[Q], yn[Q], zn[Q], b1[Q], b2[Q];
#pragma unroll
    for (int q = 0; q < Q; ++q) {
        int n = qbase + q * TPB + tid;
        xn[q] = basep[n * 3 + 0];
        yn[q] = basep[n * 3 + 1];
        zn[q] = basep[n * 3 + 2];
        b1[q] = BIGD; b2[q] = BIGD;
    }
    __syncthreads();

    for (int p = 0; p < CHUNKSZ; p += 8) {
        float4 c[8];
#pragma unroll
        for (int j = 0; j < 8; ++j) c[j] = pts[p + j];
#pragma unroll
        for (int j = 0; j < 8; ++j) {
#pragma unroll
            for (int q = 0; q < Q; ++q) {
                float k = cand_key(c[j].x, c[j].y, c[j].z, c[j].w, xn[q], yn[q], zn[q]);
                b2[q] = fminf(fmaxf(k, b1[q]), b2[q]);
                b1[q] = fminf(k, b1[q]);
            }
        }
    }

#pragma unroll
    for (int q = 0; q < Q; ++q) {
        int n = qbase + q * TPB + tid;
        partial[(size_t)chunk * TOTQ + (size_t)b * NPTS + n] = make_float2(b1[q], b2[q]);
    }
}

// Rescan one chunk from LDS-staged points with full index tracking, bitwise
// identical key arithmetic, excluding self. Feeds ascending m (stable).
template <int CHUNKSZ>
__device__ __forceinline__ void rescan_chunk_lds(const float4* __restrict__ pts, int c, int n,
                                                 float xn, float yn, float zn,
                                                 float& r1, int& j1, float& r2, int& j2) {
    r1 = BIGD; r2 = BIGD; j1 = 0; j2 = 0;
    const int m0 = c * CHUNKSZ;
#pragma unroll 4
    for (int m = m0; m < m0 + CHUNKSZ; ++m) {
        float4 cd = pts[m];   // per-lane divergent LDS read (lanes own chunks)
        float k = cand_key(cd.x, cd.y, cd.z, cd.w, xn, yn, zn);
        k = (m == n) ? BIGD : k;
        top2min(k, m, r1, j1, r2, j2);
    }
}

// Pass 2: one block serves 256 queries of ONE batch. Stage all 4096 staged
// points in 64 KB LDS, merge chunk VALUE pairs (self chunk skipped), find the
// <=2 winning chunks, rescan them + self chunk from LDS with index tracking
// (ascending chunk order = stable), gather coords, write all four outputs.
template <int NCHUNKS>
__global__ __launch_bounds__(TPB) void knn_merge(const float* __restrict__ coords,
                                                 const float2* __restrict__ partial,
                                                 float* __restrict__ out) {
    constexpr int CHUNKSZ = NPTS / NCHUNKS;
    __shared__ float4 pts[NPTS];  // 64 KB
    const int tid = (int)threadIdx.x;
    const int q = blockIdx.x * TPB + tid;   // 0..TOTQ-1
    const int b = q >> 12;                  // block-uniform (16 blocks per batch)
    const int n = q & (NPTS - 1);
    const float* basep = coords + (size_t)b * NPTS * 3;

    for (int p = tid; p < NPTS; p += TPB) {
        float x = basep[p * 3 + 0];
        float y = basep[p * 3 + 1];
        float z = basep[p * 3 + 2];
        pts[p] = make_float4(-2.0f * x, -2.0f * y, -2.0f * z, cand_w(x, y, z));
    }

    const float xn = basep[n * 3 + 0];
    const float yn = basep[n * 3 + 1];
    const float zn = basep[n * 3 + 2];
    const int c_self = n / CHUNKSZ;   // wave-uniform (CHUNKSZ multiple of 64)
    __syncthreads();

    // Value merge with chunk attribution, self chunk skipped (coalesced reads).
    float v1 = BIGD, v2 = BIGD;
    int ca = (c_self == 0) ? 1 : 0, cbk = ca;
    for (int c = 0; c < NCHUNKS; ++c) {
        if (c == c_self) continue;   // wave-uniform branch
        float2 v = partial[(size_t)c * TOTQ + q];
        top2min(v.x, c, v1, ca, v2, cbk);
        top2min(v.y, c, v1, ca, v2, cbk);
    }

    // Rescan set = {c_self, ca, cbk}, ascending with dedup (ca,cbk != c_self).
    int lo3 = min(min(c_self, ca), cbk);
    int hi3 = max(max(c_self, ca), cbk);
    int md3 = c_self + ca + cbk - lo3 - hi3;

    float f1 = BIGD, f2 = BIGD;
    int g1 = 0, g2 = 0;
    float r1, r2; int j1, j2;

    rescan_chunk_lds<CHUNKSZ>(pts, lo3, n, xn, yn, zn, r1, j1, r2, j2);
    top2min(r1, j1, f1, g1, f2, g2);
    top2min(r2, j2, f1, g1, f2, g2);
    if (md3 > lo3) {
        rescan_chunk_lds<CHUNKSZ>(pts, md3, n, xn, yn, zn, r1, j1, r2, j2);
        top2min(r1, j1, f1, g1, f2, g2);
        top2min(r2, j2, f1, g1, f2, g2);
    }
    if (hi3 > md3) {
        rescan_chunk_lds<CHUNKSZ>(pts, hi3, n, xn, yn, zn, r1, j1, r2, j2);
        top2min(r1, j1, f1, g1, f2, g2);
        top2min(r2, j2, f1, g1, f2, g2);
    }

    float* A  = out;
    float* C  = out + (size_t)TOTQ * 3;
    float* I1 = out + (size_t)2 * TOTQ * 3;
    float* I2 = I1 + (size_t)TOTQ;

    // Gather from LDS: -0.5f * (-2x) is exact.
    float4 p1 = pts[g1];
    float4 p2 = pts[g2];
    A[(size_t)q * 3 + 0] = -0.5f * p1.x;
    A[(size_t)q * 3 + 1] = -0.5f * p1.y;
    A[(size_t)q * 3 + 2] = -0.5f * p1.z;
    C[(size_t)q * 3 + 0] = -0.5f * p2.x;
    C[(size_t)q * 3 + 1] = -0.5f * p2.y;
    C[(size_t)q * 3 + 2] = -0.5f * p2.z;
    I1[q] = (float)g1;
    I2[q] = (float)g2;
}

// Ultimate fallback (tiny ws): monolithic kernel, all candidates in LDS.
__global__ __launch_bounds__(TPB) void knn_full(const float* __restrict__ coords,
                                                float* __restrict__ out) {
    __shared__ float4 pts[NPTS];  // 64 KB
    const int tid  = (int)threadIdx.x;
    const int tile = blockIdx.x;
    const int b    = blockIdx.y;
    const float* basep = coords + (size_t)b * NPTS * 3;

    for (int p = tid; p < NPTS; p += TPB) {
        float x = basep[p * 3 + 0];
        float y = basep[p * 3 + 1];
        float z = basep[p * 3 + 2];
        pts[p] = make_float4(-2.0f * x, -2.0f * y, -2.0f * z, cand_w(x, y, z));
    }
    const int n = tile * TPB + tid;
    const float xn = basep[n * 3 + 0];
    const float yn = basep[n * 3 + 1];
    const float zn = basep[n * 3 + 2];
    __syncthreads();

    float b1 = BIGD, b2 = BIGD;
    int i1 = 0, i2 = 0;
    for (int p = 0; p < NPTS; p += 4) {
#pragma unroll
        for (int j = 0; j < 4; ++j) {
            float4 c = pts[p + j];
            float k = cand_key(c.x, c.y, c.z, c.w, xn, yn, zn);
            k = (p + j == n) ? BIGD : k;
            top2min(k, p + j, b1, i1, b2, i2);
        }
    }

    const int q = b * NPTS + n;
    float* A  = out;
    float* C  = out + (size_t)TOTQ * 3;
    float* I1 = out + (size_t)2 * TOTQ * 3;
    float* I2 = I1 + (size_t)TOTQ;
    float4 p1 = pts[i1];
    float4 p2 = pts[i2];
    A[(size_t)q * 3 + 0] = -0.5f * p1.x;
    A[(size_t)q * 3 + 1] = -0.5f * p1.y;
    A[(size_t)q * 3 + 2] = -0.5f * p1.z;
    C[(size_t)q * 3 + 0] = -0.5f * p2.x;
    C[(size_t)q * 3 + 1] = -0.5f * p2.y;
    C[(size_t)q * 3 + 2] = -0.5f * p2.z;
    I1[q] = (float)i1;
    I2[q] = (float)i2;
}

extern "C" void kernel_launch(void* const* d_in, const int* in_sizes, int n_in,
                              void* d_out, int out_size, void* d_ws, size_t ws_size,
                              hipStream_t stream) {
    const float* coords = (const float*)d_in[0];
    float* out = (float*)d_out;
    float2* partial = (float2*)d_ws;
    const size_t chunk_bytes = (size_t)TOTQ * sizeof(float2);  // 256 KB per chunk

    if (ws_size >= 64 * chunk_bytes) {
        // 16 MB: NCHUNKS=64, Q=8 -> grid 2*64*8 = 1024 blocks (4/CU)
        hipLaunchKernelGGL((knn_scan<64, 8>), dim3(2, 64, BATCH), dim3(TPB), 0, stream,
                           coords, partial);
        hipLaunchKernelGGL((knn_merge<64>), dim3(TOTQ / TPB), dim3(TPB), 0, stream,
                           coords, partial, out);
    } else if (ws_size >= 32 * chunk_bytes) {
        // 8 MB: NCHUNKS=32, Q=8 -> 512 blocks
        hipLaunchKernelGGL((knn_scan<32, 8>), dim3(2, 32, BATCH), dim3(TPB), 0, stream,
                           coords, partial);
        hipLaunchKernelGGL((knn_merge<32>), dim3(TOTQ / TPB), dim3(TPB), 0, stream,
                           coords, partial, out);
    } else {
        hipLaunchKernelGGL(knn_full, dim3(NPTS / TPB, BATCH), dim3(TPB), 0, stream,
                           coords, out);
    }
}